// Round 6
// baseline (135.711 us; speedup 1.0000x reference)
//
#include <hip/hip_runtime.h>
#include <hip/hip_bf16.h>

#define T_TOK 2048
#define DDIM  1024
#define IDIM  1024
#define NEXP  8
#define TOPK  2
#define MAXROWS (T_TOK * TOPK)

#define BM 64
#define BN 64
#define BK 32

typedef __attribute__((ext_vector_type(8))) short          s16x8;
typedef __attribute__((ext_vector_type(8))) unsigned short u16x8;
typedef __attribute__((ext_vector_type(4))) float          f32x4;

__device__ __forceinline__ unsigned short f2bf(float f) {
    return __builtin_bit_cast(unsigned short, __float2bfloat16(f));
}

__device__ __forceinline__ u16x8 pack8(const float4& a, const float4& b) {
    u16x8 v;
    v[0] = f2bf(a.x); v[1] = f2bf(a.y); v[2] = f2bf(a.z); v[3] = f2bf(a.w);
    v[4] = f2bf(b.x); v[5] = f2bf(b.y); v[6] = f2bf(b.z); v[7] = f2bf(b.w);
    return v;
}

__device__ __forceinline__ s16x8 cvt8(const float4& a, const float4& b) {
    return __builtin_bit_cast(s16x8, pack8(a, b));
}

// async global -> LDS, 16 B per lane. Global address is PER-LANE; LDS dest is
// wave-uniform base + lane*16 (linear).
__device__ __forceinline__ void gll16(const void* g, void* l) {
    __builtin_amdgcn_global_load_lds(
        (const __attribute__((address_space(1))) void*)g,
        (__attribute__((address_space(3))) void*)l, 16, 0, 0);
}

// ---------------- routing: build per-expert compact token lists ----------------
__global__ void route_kernel(const int* __restrict__ indices,
                             const float* __restrict__ weights,
                             const void* __restrict__ mask,
                             int* __restrict__ counts, int* __restrict__ offsets,
                             int* __restrict__ tok, float* __restrict__ wslot) {
    __shared__ int cnt[NEXP], offs[NEXP], cur[NEXP];
    __shared__ int is_u8;
    const int tid = threadIdx.x;
    const unsigned char* m8  = (const unsigned char*)mask;
    const int*           m32 = (const int*)mask;
    if (tid < NEXP) cnt[tid] = 0;
    if (tid == 0) is_u8 = 0;
    __syncthreads();
    int found = 0;
    for (int i = tid; i < T_TOK; i += blockDim.x)
        if ((i & 3) != 0 && m8[i] != 0) found = 1;
    if (found) atomicOr(&is_u8, 1);
    __syncthreads();
    const int u8mode = is_u8;
    for (int idx = tid; idx < MAXROWS; idx += blockDim.x) {
        int t = idx >> 1;  // K = 2
        int active = u8mode ? (m8[t] != 0) : (m32[t] != 0);
        if (active) atomicAdd(&cnt[indices[idx]], 1);
    }
    __syncthreads();
    if (tid == 0) {
        int run = 0;
        for (int e = 0; e < NEXP; ++e) { offs[e] = run; run += cnt[e]; }
    }
    __syncthreads();
    if (tid < NEXP) { counts[tid] = cnt[tid]; offsets[tid] = offs[tid]; cur[tid] = offs[tid]; }
    __syncthreads();
    for (int idx = tid; idx < MAXROWS; idx += blockDim.x) {
        int t = idx >> 1;
        int active = u8mode ? (m8[t] != 0) : (m32[t] != 0);
        if (active) {
            int e = indices[idx];
            int p = atomicAdd(&cur[e], 1);
            tok[p]   = t;
            wslot[p] = weights[idx];
        }
    }
}

// ---------------- x: f32 -> bf16 once ----------------
__global__ __launch_bounds__(256) void cvt_x_kernel(const float* __restrict__ x,
                                                    unsigned short* __restrict__ xb) {
    int i = (blockIdx.x * 256 + threadIdx.x) * 8;
    float4 a = *reinterpret_cast<const float4*>(x + i);
    float4 b = *reinterpret_cast<const float4*>(x + i + 4);
    *reinterpret_cast<u16x8*>(xb + i) = pack8(a, b);
}

// LDS layouts (all rows are 128 B, XOR-swizzled by slot ^= row&7, rule #21):
//  A tile (bf16, 64 tok-rows x 32): LDS [32 rows][8 slots x 16B]; LDS-row r holds
//   tokens {2r, 2r+1}; logical slot il = 2*kslot + (tok&1); stored at il ^ (r&7).
//  B tile (f32, 64 rows x 32): LDS [64 rows][8 slots x 16B]; logical slot il = k/4;
//   stored at il ^ (row&7).

// ---------------- GEMM1: H = silu(X G^T) * (X U^T), gll-staged dbuf ----------------
__global__ __launch_bounds__(256) void gemm1_kernel(
    const unsigned short* __restrict__ xb,
    const float* __restrict__ gate, const float* __restrict__ up,
    const int* __restrict__ counts, const int* __restrict__ offsets,
    const int* __restrict__ tok, unsigned short* __restrict__ hb) {
    const int e     = blockIdx.z;
    const int n_e   = counts[e];
    const int tileM = blockIdx.y;
    if (tileM * BM >= n_e) return;
    const int off = offsets[e];
    const int n0  = blockIdx.x * BN;

    __shared__ unsigned short lA[2][2048];  // 2 x 4 KB
    __shared__ float          lG[2][2048];  // 2 x 8 KB
    __shared__ float          lU[2][2048];  // 2 x 8 KB

    const int tid  = threadIdx.x;
    const int lane = tid & 63;
    const int wid  = tid >> 6;
    const int wm   = wid >> 1, wn = wid & 1;

    // ---- staging source addresses (per-lane, pre-swizzled) ----
    // A: wave wid stages chunk wid (LDS rows 8*wid .. 8*wid+7)
    const int rA  = wid * 8 + (lane >> 3);
    const int ilA = (lane & 7) ^ (rA & 7);
    const int trA = 2 * rA + (ilA & 1);
    {   }
    const int rowIdxA = tileM * BM + trA;
    const int tIdxA = (rowIdxA < n_e) ? tok[off + rowIdxA] : tok[off];
    const unsigned short* aSrc = xb + (size_t)tIdxA * DDIM + (ilA >> 1) * 8;
    // B: wave wid stages chunks {2*wid, 2*wid+1} (rows 16*wid .. 16*wid+15)
    const int rB0 = (2 * wid) * 8 + (lane >> 3);
    const int rB1 = rB0 + 8;
    const int ilB0 = (lane & 7) ^ (rB0 & 7);
    const int ilB1 = (lane & 7) ^ (rB1 & 7);
    const float* gSrc0 = gate + ((size_t)e * IDIM + n0 + rB0) * DDIM + ilB0 * 4;
    const float* gSrc1 = gate + ((size_t)e * IDIM + n0 + rB1) * DDIM + ilB1 * 4;
    const float* uSrc0 = up   + ((size_t)e * IDIM + n0 + rB0) * DDIM + ilB0 * 4;
    const float* uSrc1 = up   + ((size_t)e * IDIM + n0 + rB1) * DDIM + ilB1 * 4;

    f32x4 accg[2][2] = {};
    f32x4 accu[2][2] = {};

    const int fr = lane & 15;
    const int s8 = lane >> 4;       // k-slot 0..3 (8 bf16 / 8 f32... per 2 reads)

    auto STAGE = [&](int b, int t) {
        const int k0 = t * BK;      // elems (shorts for A, floats for B)
        gll16(aSrc  + k0, &lA[b][wid * 512]);
        gll16(gSrc0 + k0, &lG[b][(2 * wid) * 256]);
        gll16(gSrc1 + k0, &lG[b][(2 * wid + 1) * 256]);
        gll16(uSrc0 + k0, &lU[b][(2 * wid) * 256]);
        gll16(uSrc1 + k0, &lU[b][(2 * wid + 1) * 256]);
    };

    auto COMPUTE = [&](int b) {
        s16x8 a[2];
#pragma unroll
        for (int m = 0; m < 2; ++m) {
            int trow = wm * 32 + m * 16 + fr;
            int r = trow >> 1, p = trow & 1;
            int is_ = (2 * s8 + p) ^ (r & 7);
            a[m] = *reinterpret_cast<const s16x8*>(&lA[b][r * 64 + is_ * 8]);
        }
        s16x8 bg[2], bu[2];
#pragma unroll
        for (int nf = 0; nf < 2; ++nf) {
            int n = wn * 32 + nf * 16 + fr;
            int xr = n & 7;
            float4 g0 = *reinterpret_cast<const float4*>(&lG[b][n * 32 + ((2 * s8) ^ xr) * 4]);
            float4 g1 = *reinterpret_cast<const float4*>(&lG[b][n * 32 + ((2 * s8 + 1) ^ xr) * 4]);
            float4 u0 = *reinterpret_cast<const float4*>(&lU[b][n * 32 + ((2 * s8) ^ xr) * 4]);
            float4 u1 = *reinterpret_cast<const float4*>(&lU[b][n * 32 + ((2 * s8 + 1) ^ xr) * 4]);
            bg[nf] = cvt8(g0, g1);
            bu[nf] = cvt8(u0, u1);
        }
#pragma unroll
        for (int m = 0; m < 2; ++m)
#pragma unroll
            for (int nf = 0; nf < 2; ++nf) {
                accg[m][nf] = __builtin_amdgcn_mfma_f32_16x16x32_bf16(a[m], bg[nf], accg[m][nf], 0, 0, 0);
                accu[m][nf] = __builtin_amdgcn_mfma_f32_16x16x32_bf16(a[m], bu[nf], accu[m][nf], 0, 0, 0);
            }
    };

    const int NT = DDIM / BK;  // 32
    STAGE(0, 0);
    __syncthreads();
    for (int t = 0; t < NT - 1; ++t) {
        STAGE((t + 1) & 1, t + 1);   // async into other buffer, in flight over COMPUTE
        COMPUTE(t & 1);
        __syncthreads();             // drains vmcnt+lgkm once per iter
    }
    COMPUTE((NT - 1) & 1);

    const int rbase = tileM * BM;
#pragma unroll
    for (int m = 0; m < 2; ++m)
#pragma unroll
        for (int n = 0; n < 2; ++n)
#pragma unroll
            for (int j = 0; j < 4; ++j) {
                int rl = wm * 32 + m * 16 + (lane >> 4) * 4 + j;
                if (rbase + rl < n_e) {
                    int col = wn * 32 + n * 16 + fr;
                    float g = accg[m][n][j];
                    float u = accu[m][n][j];
                    float h = (g / (1.0f + __expf(-g))) * u;
                    hb[(size_t)(off + rbase + rl) * IDIM + n0 + col] = f2bf(h);
                }
            }
}

// ---------------- GEMM2: Y_rows = H D^T, weighted scatter-add, gll-staged dbuf ----------------
__global__ __launch_bounds__(256) void gemm2_kernel(
    const unsigned short* __restrict__ hb, const float* __restrict__ down,
    const int* __restrict__ counts, const int* __restrict__ offsets,
    const int* __restrict__ tok, const float* __restrict__ wslot,
    float* __restrict__ y) {
    const int e     = blockIdx.z;
    const int n_e   = counts[e];
    const int tileM = blockIdx.y;
    if (tileM * BM >= n_e) return;
    const int off = offsets[e];
    const int n0  = blockIdx.x * BN;

    __shared__ unsigned short lA[2][2048];
    __shared__ float          lB[2][2048];

    const int tid  = threadIdx.x;
    const int lane = tid & 63;
    const int wid  = tid >> 6;
    const int wm   = wid >> 1, wn = wid & 1;

    const int rA  = wid * 8 + (lane >> 3);
    const int ilA = (lane & 7) ^ (rA & 7);
    const int trA = 2 * rA + (ilA & 1);
    const int rowIdxA = tileM * BM + trA;
    const int hrowA = (rowIdxA < n_e) ? (off + rowIdxA) : off;
    const unsigned short* aSrc = hb + (size_t)hrowA * IDIM + (ilA >> 1) * 8;
    const int rB0 = (2 * wid) * 8 + (lane >> 3);
    const int rB1 = rB0 + 8;
    const int ilB0 = (lane & 7) ^ (rB0 & 7);
    const int ilB1 = (lane & 7) ^ (rB1 & 7);
    const float* bSrc0 = down + ((size_t)e * DDIM + n0 + rB0) * IDIM + ilB0 * 4;
    const float* bSrc1 = down + ((size_t)e * DDIM + n0 + rB1) * IDIM + ilB1 * 4;

    f32x4 acc[2][2] = {};

    const int fr = lane & 15;
    const int s8 = lane >> 4;

    auto STAGE = [&](int b, int t) {
        const int k0 = t * BK;
        gll16(aSrc  + k0, &lA[b][wid * 512]);
        gll16(bSrc0 + k0, &lB[b][(2 * wid) * 256]);
        gll16(bSrc1 + k0, &lB[b][(2 * wid + 1) * 256]);
    };

    auto COMPUTE = [&](int b) {
        s16x8 a[2];
#pragma unroll
        for (int m = 0; m < 2; ++m) {
            int trow = wm * 32 + m * 16 + fr;
            int r = trow >> 1, p = trow & 1;
            int is_ = (2 * s8 + p) ^ (r & 7);
            a[m] = *reinterpret_cast<const s16x8*>(&lA[b][r * 64 + is_ * 8]);
        }
        s16x8 bf[2];
#pragma unroll
        for (int nf = 0; nf < 2; ++nf) {
            int n = wn * 32 + nf * 16 + fr;
            int xr = n & 7;
            float4 b0 = *reinterpret_cast<const float4*>(&lB[b][n * 32 + ((2 * s8) ^ xr) * 4]);
            float4 b1 = *reinterpret_cast<const float4*>(&lB[b][n * 32 + ((2 * s8 + 1) ^ xr) * 4]);
            bf[nf] = cvt8(b0, b1);
        }
#pragma unroll
        for (int m = 0; m < 2; ++m)
#pragma unroll
            for (int nf = 0; nf < 2; ++nf)
                acc[m][nf] = __builtin_amdgcn_mfma_f32_16x16x32_bf16(a[m], bf[nf], acc[m][nf], 0, 0, 0);
    };

    const int NT = IDIM / BK;
    STAGE(0, 0);
    __syncthreads();
    for (int t = 0; t < NT - 1; ++t) {
        STAGE((t + 1) & 1, t + 1);
        COMPUTE(t & 1);
        __syncthreads();
    }
    COMPUTE((NT - 1) & 1);

    const int rbase = tileM * BM;
#pragma unroll
    for (int m = 0; m < 2; ++m)
#pragma unroll
        for (int n = 0; n < 2; ++n)
#pragma unroll
            for (int j = 0; j < 4; ++j) {
                int rl = wm * 32 + m * 16 + (lane >> 4) * 4 + j;
                if (rbase + rl < n_e) {
                    int col = wn * 32 + n * 16 + fr;
                    int row = off + rbase + rl;
                    float v = acc[m][n][j] * wslot[row];
                    atomicAdd(&y[(size_t)tok[row] * DDIM + n0 + col], v);
                }
            }
}

extern "C" void kernel_launch(void* const* d_in, const int* in_sizes, int n_in,
                              void* d_out, int out_size, void* d_ws, size_t ws_size,
                              hipStream_t stream) {
    const float* x       = (const float*)d_in[0];
    const void*  mask    = d_in[1];
    const float* weights = (const float*)d_in[2];
    const int*   indices = (const int*)d_in[3];
    const float* gate    = (const float*)d_in[4];
    const float* up      = (const float*)d_in[5];
    const float* down    = (const float*)d_in[6];
    float*       y       = (float*)d_out;

    char* ws = (char*)d_ws;
    int*            counts  = (int*)ws;
    int*            offsets = (int*)(ws + 32);
    int*            tok     = (int*)(ws + 256);
    float*          wslot   = (float*)(ws + 256 + MAXROWS * 4);
    unsigned short* xb      = (unsigned short*)(ws + 65536);
    unsigned short* hb      = (unsigned short*)(ws + 65536 + (size_t)T_TOK * DDIM * 2);

    hipMemsetAsync(d_out, 0, (size_t)out_size * sizeof(float), stream);
    route_kernel<<<1, 256, 0, stream>>>(indices, weights, mask, counts, offsets, tok, wslot);
    cvt_x_kernel<<<(T_TOK * DDIM / 8) / 256, 256, 0, stream>>>(x, xb);

    dim3 g1(IDIM / BN, MAXROWS / BM, NEXP);
    gemm1_kernel<<<g1, 256, 0, stream>>>(xb, gate, up, counts, offsets, tok, hb);
    dim3 g2(DDIM / BN, MAXROWS / BM, NEXP);
    gemm2_kernel<<<g2, 256, 0, stream>>>(hb, down, counts, offsets, tok, wslot, y);
}